// Round 1
// baseline (544.616 us; speedup 1.0000x reference)
//
#include <hip/hip_runtime.h>
#include <math.h>

// B=32, D=2048 rank-1 self-attention, fp32.
//   k2_j = k_j*log2e ; m2_j = k2_j>=0 ? k2_j*qmax : k2_j*qmin
//   Z_j  = sum_i 2^(q_i k2_j - m2_j) ; d_j = log2(|v_j|/Z_j) - m2_j
//   out_i = sum_{j:v>0} 2^(fma(q_i,k2_j,d_j)) - sum_{j:v<0} 2^(...)
//
// R12: scalar-pipe restructure of the two O(D^2) exp2 passes.
//  - NEW k2_fin (768 blocks): sums the 4 splitK parts ONCE into final
//    qf/kf(pre-scaled by log2e)/vf arrays + per-256-chunk q minmax partials
//    + zeroes the pos/neg counters. Removes the 32x-redundant q staging +
//    minmax that every k3 block used to redo (33 MB of part re-reads).
//  - k3_z: inner loop reads q via wave-UNIFORM addresses from const
//    __restrict__ global (ih = readfirstlane(t>>6)) -> s_load candidates,
//    no LDS q buffer, no barrier before the hot loop. fma(q_s,k2_v,nm2_v)
//    keeps <=1 SGPR operand per VALU op.
//  - Partition is now per-BATCH global pos/neg float2 arrays with
//    global-atomic slot alloc (compiler wave-aggregates). No SEGF pads,
//    no npos table, 2048 exact entries instead of 2176.
//  - k4_out: waves stride the pos/neg streams with uniform g -> uniform
//    float4 loads (s_load_dwordx8 candidates), per-lane qi in VGPR;
//    remainder (<=3 entries) handled by wave 0 (pos) / wave 1 (neg).
// k1 unchanged (W-stream port-limited, ~8-12us).

#define D 2048
#define BATCH 32
#define NPART 4

// workspace float offsets
#define PART_STRIDE 196608   // one splitK part: 3*65536 (m*65536 + b*D + r)
#define QF_OFF  786432       // qf[32][2048]
#define KF_OFF  851968       // k2f[32][2048]  (pre-scaled by log2e)
#define VF_OFF  917504       // vf[32][2048]
#define QMM_OFF 983040       // qmm[32][8] float2 (mx,mn per 256-chunk)
#define CNT_OFF 983552       // 64 ints: (npos,nneg) per batch
#define PKD_OFF 983616       // float2[32][2048] pos (k2,d)
#define NKD_OFF 1114688      // float2[32][2048] neg (k2,d)

#define L2E 1.4426950408889634f

typedef short s16x8 __attribute__((ext_vector_type(8)));
typedef float f32x4 __attribute__((ext_vector_type(4)));

union FragU { s16x8 v; unsigned u[4]; };

__device__ __forceinline__ float fast_exp2(float x) {
#if __has_builtin(__builtin_amdgcn_exp2f)
  return __builtin_amdgcn_exp2f(x);
#else
  return exp2f(x);
#endif
}
// pack two fp32 into one VGPR of two RNE-rounded bf16
__device__ __forceinline__ unsigned pack_rne(float a, float b) {
  unsigned ua = __float_as_uint(a), ub = __float_as_uint(b);
  ua = ua + 0x7FFFu + ((ua >> 16) & 1u);
  ub = ub + 0x7FFFu + ((ub >> 16) & 1u);
  return (ua >> 16) | (ub & 0xFFFF0000u);
}
__device__ __forceinline__ void pack8(const float4& fa, const float4& fb,
                                      FragU& h) {
  h.u[0] = pack_rne(fa.x, fa.y);
  h.u[1] = pack_rne(fa.z, fa.w);
  h.u[2] = pack_rne(fb.x, fb.y);
  h.u[3] = pack_rne(fb.z, fb.w);
}

// ---------------- K1: projections via LDS-free bf16 MFMA -------------------
// grid 1536 = 384 row-tiles(16 rows) x 4 K-quarters. 4 waves/block, wave wv
// covers K [kq*512 + wv*128, +128), 4 steps of 32. ALL 24 float4 (W + x)
// prefetched to registers before any pack/MFMA -> single vmcnt drain.
__global__ __launch_bounds__(256, 2) void k1_proj(
    const float* __restrict__ x, const float* __restrict__ Wq,
    const float* __restrict__ Wk, const float* __restrict__ Wv,
    float* __restrict__ ws) {
  __shared__ float red[4][512];
  const int tid = threadIdx.x;
  const int lane = tid & 63, wv = tid >> 6;
  const int tile = blockIdx.x >> 2, kq = blockIdx.x & 3;
  const int m = tile >> 7, lr = (tile & 127) * 16;
  const float* W = (m == 0) ? Wq : (m == 1) ? Wk : Wv;

  const int kbase = kq * 512 + wv * 128 + (lane >> 4) * 8;
  const float* ap = W + (size_t)(lr + (lane & 15)) * D + kbase;
  const float* xp0 = x + (size_t)(lane & 15) * D + kbase;
  const float* xp1 = xp0 + 16 * D;

  float4 fa[4], fb[4], x0a[4], x0b[4], x1a[4], x1b[4];
#pragma unroll
  for (int s = 0; s < 4; ++s) {          // issue all 24 loads back-to-back
    const int off = s * 32;
    fa[s] = *(const float4*)(ap + off);
    fb[s] = *(const float4*)(ap + off + 4);
    x0a[s] = *(const float4*)(xp0 + off);
    x0b[s] = *(const float4*)(xp0 + off + 4);
    x1a[s] = *(const float4*)(xp1 + off);
    x1b[s] = *(const float4*)(xp1 + off + 4);
  }

  f32x4 acc0 = {0.f, 0.f, 0.f, 0.f}, acc1 = {0.f, 0.f, 0.f, 0.f};
#pragma unroll
  for (int s = 0; s < 4; ++s) {
    FragU Ah, Bh0, Bh1;
    pack8(fa[s], fb[s], Ah);
    pack8(x0a[s], x0b[s], Bh0);
    pack8(x1a[s], x1b[s], Bh1);
    acc0 = __builtin_amdgcn_mfma_f32_16x16x32_bf16(Ah.v, Bh0.v, acc0, 0, 0, 0);
    acc1 = __builtin_amdgcn_mfma_f32_16x16x32_bf16(Ah.v, Bh1.v, acc1, 0, 0, 0);
  }
  // C/D: col = lane&15 (batch), row = (lane>>4)*4 + reg (weight row)
  const int col = lane & 15, rq = (lane >> 4) * 4;
#pragma unroll
  for (int r = 0; r < 4; ++r) {
    red[wv][col * 16 + rq + r] = acc0[r];
    red[wv][(col + 16) * 16 + rq + r] = acc1[r];
  }
  __syncthreads();
  float* part = ws + (size_t)kq * PART_STRIDE + (size_t)m * 65536;
#pragma unroll
  for (int i = tid; i < 512; i += 256) {
    float s = (red[0][i] + red[1][i]) + (red[2][i] + red[3][i]);
    part[(size_t)(i >> 4) * D + lr + (i & 15)] = s;
  }
}

// ---------------- K2: finalize q/k/v once + q-minmax partials --------------
// grid 768 = 3 matrices x 32 batches x 8 chunks(256). One element/thread.
// m==0 blocks also reduce per-chunk q minmax and zero the partition
// counters (k3 depends on both; stream order guarantees visibility).
__global__ __launch_bounds__(256) void k2_fin(float* __restrict__ ws,
                                              const float* __restrict__ bq,
                                              const float* __restrict__ bk,
                                              const float* __restrict__ bv) {
  __shared__ float smx[4], smn[4];
  const int id = blockIdx.x, t = threadIdx.x;
  const int m = id >> 8, r = id & 255, b = r >> 3, c = r & 7;
  const int i = c * 256 + t;
  const size_t e = (size_t)m * 65536 + (size_t)b * D + i;
  float s = (ws[e] + ws[e + PART_STRIDE]) +
            (ws[e + 2 * PART_STRIDE] + ws[e + 3 * PART_STRIDE]);
  if (m == 0) {
    s += bq[i];
    ws[QF_OFF + (size_t)b * D + i] = s;
    float mx = s, mn = s;
#pragma unroll
    for (int off = 32; off; off >>= 1) {
      mx = fmaxf(mx, __shfl_down(mx, off));
      mn = fminf(mn, __shfl_down(mn, off));
    }
    if ((t & 63) == 0) { smx[t >> 6] = mx; smn[t >> 6] = mn; }
    __syncthreads();
    if (t == 0) {
      mx = fmaxf(fmaxf(smx[0], smx[1]), fmaxf(smx[2], smx[3]));
      mn = fminf(fminf(smn[0], smn[1]), fminf(smn[2], smn[3]));
      float* qm = ws + QMM_OFF + (size_t)(b * 8 + c) * 2;
      qm[0] = mx; qm[1] = mn;
    }
    if (c == 0 && t < 2) ((int*)(ws + CNT_OFF))[b * 2 + t] = 0;
  } else if (m == 1) {
    ws[KF_OFF + (size_t)b * D + i] = (s + bk[i]) * L2E;
  } else {
    ws[VF_OFF + (size_t)b * D + i] = s + bv[i];
  }
}

// ---------------- K3: Z + finalize d_j + global pos/neg partition ----------
// grid 1024: b = bx>>5, jc = bx&31 (64 j). Thread t: j = jc*64+(t&63),
// i-eighth ih = readfirstlane(t>>6) -> wave-uniform q addresses (scalar-load
// eligible: qf is const __restrict__, stores go through distinct restrict
// pointers). 8-way LDS Z combine; t<64 appends (k2,d) to the per-batch
// pos/neg stream via global atomic slot alloc (wave-aggregated).
__global__ __launch_bounds__(512, 8) void k3_z(
    const float* __restrict__ qf, const float* __restrict__ kf,
    const float* __restrict__ vf, const float* __restrict__ qmm,
    int* __restrict__ cnt, float2* __restrict__ pkd,
    float2* __restrict__ nkd) {
  __shared__ float zs[512];
  const int bx = blockIdx.x, t = threadIdx.x;
  const int b = bx >> 5, jc = bx & 31;
  const int jl = t & 63;
  const int ih = __builtin_amdgcn_readfirstlane(t >> 6);
  const int j = jc * 64 + jl;
  const float k2 = kf[(size_t)b * D + j];
  const float* qm = qmm + b * 16;
  float mx = qm[0], mn = qm[1];
#pragma unroll
  for (int w = 1; w < 8; ++w) {
    mx = fmaxf(mx, qm[2 * w]);
    mn = fminf(mn, qm[2 * w + 1]);
  }
  const float m2 = (k2 >= 0.f) ? k2 * mx : k2 * mn;
  const float nm2 = -m2;
  const float* qp = qf + (size_t)b * D + ih * 256;
  float z0 = 0.f, z1 = 0.f, z2 = 0.f, z3 = 0.f;
#pragma unroll 8
  for (int i2 = 0; i2 < 256; i2 += 4) {
    float4 q4 = *(const float4*)(qp + i2);  // wave-uniform address
    z0 += fast_exp2(fmaf(q4.x, k2, nm2));
    z1 += fast_exp2(fmaf(q4.y, k2, nm2));
    z2 += fast_exp2(fmaf(q4.z, k2, nm2));
    z3 += fast_exp2(fmaf(q4.w, k2, nm2));
  }
  zs[t] = (z0 + z1) + (z2 + z3);
  __syncthreads();
  if (t < 64) {
    float Z = ((zs[t] + zs[t + 64]) + (zs[t + 128] + zs[t + 192])) +
              ((zs[t + 256] + zs[t + 320]) + (zs[t + 384] + zs[t + 448]));
    const float v = vf[(size_t)b * D + j];
    const float d = __log2f(fabsf(v) / Z) - m2;  // v==0 -> -inf -> 2^ -> 0
    if (v >= 0.f) {
      int s = atomicAdd(&cnt[b * 2], 1);
      pkd[(size_t)b * D + s] = make_float2(k2, d);
    } else {
      int s = atomicAdd(&cnt[b * 2 + 1], 1);
      nkd[(size_t)b * D + s] = make_float2(k2, d);
    }
  }
}

// ---------------- K4: out_i over the pos/neg streams -----------------------
// grid 1024: b = bx>>5, ic = bx&31 (64 i). Thread t: i = ic*64+(t&63),
// wave jh = readfirstlane(t>>6) strides groups of 4 entries -> uniform
// float4 loads from const __restrict__ streams (s_load candidates); qi is
// per-lane in VGPR. Remainders (<=3): wave 0 pos, wave 1 neg. 8-way LDS
// combine, t<64 single-writer store.
__global__ __launch_bounds__(512, 8) void k4_out(
    const float* __restrict__ qf, const int* __restrict__ cnt,
    const float2* __restrict__ pkd, const float2* __restrict__ nkd,
    float* __restrict__ out) {
  __shared__ float rs[512];
  const int bx = blockIdx.x, t = threadIdx.x;
  const int b = bx >> 5, ic = bx & 31;
  const int il = t & 63;
  const int jh = __builtin_amdgcn_readfirstlane(t >> 6);
  const int i = ic * 64 + il;
  const float qi = qf[(size_t)b * D + i];
  const int npos = cnt[b * 2], nneg = cnt[b * 2 + 1];
  const float2* pp = pkd + (size_t)b * D;
  const float2* np = nkd + (size_t)b * D;

  float p0 = 0.f, p1 = 0.f, p2 = 0.f, p3 = 0.f;
  const int GP = npos >> 2;
  for (int g = jh; g < GP; g += 8) {
    const float4* e4 = (const float4*)(pp + g * 4);  // uniform address
    float4 a = e4[0], c4 = e4[1];
    p0 += fast_exp2(fmaf(qi, a.x, a.y));
    p1 += fast_exp2(fmaf(qi, a.z, a.w));
    p2 += fast_exp2(fmaf(qi, c4.x, c4.y));
    p3 += fast_exp2(fmaf(qi, c4.z, c4.w));
  }
  if (jh == 0) {
    for (int jj = GP * 4; jj < npos; ++jj) {
      float2 e = pp[jj];
      p0 += fast_exp2(fmaf(qi, e.x, e.y));
    }
  }
  float n0 = 0.f, n1 = 0.f, n2 = 0.f, n3 = 0.f;
  const int GN = nneg >> 2;
  for (int g = jh; g < GN; g += 8) {
    const float4* e4 = (const float4*)(np + g * 4);  // uniform address
    float4 a = e4[0], c4 = e4[1];
    n0 += fast_exp2(fmaf(qi, a.x, a.y));
    n1 += fast_exp2(fmaf(qi, a.z, a.w));
    n2 += fast_exp2(fmaf(qi, c4.x, c4.y));
    n3 += fast_exp2(fmaf(qi, c4.z, c4.w));
  }
  if (jh == 1) {
    for (int jj = GN * 4; jj < nneg; ++jj) {
      float2 e = np[jj];
      n0 += fast_exp2(fmaf(qi, e.x, e.y));
    }
  }
  rs[t] = ((p0 + p1) + (p2 + p3)) - ((n0 + n1) + (n2 + n3));
  __syncthreads();
  if (t < 64)
    out[(size_t)b * D + ic * 64 + t] =
        ((rs[t] + rs[t + 64]) + (rs[t + 128] + rs[t + 192])) +
        ((rs[t + 256] + rs[t + 320]) + (rs[t + 384] + rs[t + 448]));
}

extern "C" void kernel_launch(void* const* d_in, const int* in_sizes, int n_in,
                              void* d_out, int out_size, void* d_ws, size_t ws_size,
                              hipStream_t stream) {
  (void)in_sizes; (void)n_in; (void)out_size; (void)ws_size;
  const float* x  = (const float*)d_in[0];
  const float* Wq = (const float*)d_in[1];
  const float* bq = (const float*)d_in[2];
  const float* Wk = (const float*)d_in[3];
  const float* bk = (const float*)d_in[4];
  const float* Wv = (const float*)d_in[5];
  const float* bv = (const float*)d_in[6];
  float* ws  = (float*)d_ws;
  float* out = (float*)d_out;

  k1_proj<<<1536, 256, 0, stream>>>(x, Wq, Wk, Wv, ws);
  k2_fin<<<768, 256, 0, stream>>>(ws, bq, bk, bv);
  k3_z<<<1024, 512, 0, stream>>>(ws + QF_OFF, ws + KF_OFF, ws + VF_OFF,
                                 ws + QMM_OFF, (int*)(ws + CNT_OFF),
                                 (float2*)(ws + PKD_OFF),
                                 (float2*)(ws + NKD_OFF));
  k4_out<<<1024, 512, 0, stream>>>(ws + QF_OFF, (const int*)(ws + CNT_OFF),
                                   (const float2*)(ws + PKD_OFF),
                                   (const float2*)(ws + NKD_OFF), out);
}

// Round 2
// 147.665 us; speedup vs baseline: 3.6882x; 3.6882x over previous
//
#include <hip/hip_runtime.h>
#include <math.h>

// B=32, D=2048 rank-1 self-attention, fp32.
//   k2_j = k_j*log2e ; m2_j = k2_j>=0 ? k2_j*qmax : k2_j*qmin
//   Z_j  = sum_i 2^(q_i k2_j - m2_j) ; d_j = log2(|v_j|/Z_j) - m2_j
//   out_i = sum_{j:v>0} 2^(fma(q_i,k2_j,d_j)) - sum_{j:v<0} 2^(...)
//
// R13: revert hot loops to LDS-broadcast (R11 form). R12 post-mortem:
// wave-uniform GLOBAL loads in the hot loop serialized on the per-CU
// scalar/SMEM path (1 scalar unit shared by 32 waves, lgkmcnt(0) drains,
// no cross-iteration pipelining) -> 97% stall, k3 5x slower. LDS
// ds_read_b128 broadcast is the correct uniform-operand primitive.
// Kept from R12 (off-hot-path redundancy removal):
//  - k2_fin: finalize qf / kf(pre-scaled by log2e) / vf ONCE + per-chunk
//    q-minmax partials + zero partition counters. k3 blocks now stage 8KB
//    of final qf instead of re-summing 32KB of parts + re-reducing minmax
//    (was done 32x redundantly per batch).
//  - partition into ONE two-ended per-batch stream (pos ascending from 0,
//    neg descending from 2047; npos+nneg==2048 exactly). No SEGF pads
//    (2176 -> 2048 entries), no npos table; k4 stages 16KB contiguous and
//    keeps branch-free pos/neg loops (boundary group: per-element select).
// k1 unchanged (W-stream port-limited, ~8-12us).

#define D 2048
#define BATCH 32
#define NPART 4

// workspace float offsets
#define PART_STRIDE 196608   // one splitK part: 3*65536 (m*65536 + b*D + r)
#define QF_OFF  786432       // qf[32][2048]  (q final, bias added)
#define KF_OFF  851968       // k2f[32][2048] (pre-scaled by log2e)
#define VF_OFF  917504       // vf[32][2048]
#define QMM_OFF 983040       // qmm[32][8] float2 (mx,mn per 256-chunk)
#define CNT_OFF 983552       // 64 ints: (npos,nneg) per batch
#define PKD_OFF 983616       // float2[32][2048]: pos from 0 up, neg from 2047 down

#define L2E 1.4426950408889634f

typedef short s16x8 __attribute__((ext_vector_type(8)));
typedef float f32x4 __attribute__((ext_vector_type(4)));

union FragU { s16x8 v; unsigned u[4]; };

__device__ __forceinline__ float fast_exp2(float x) {
#if __has_builtin(__builtin_amdgcn_exp2f)
  return __builtin_amdgcn_exp2f(x);
#else
  return exp2f(x);
#endif
}
// pack two fp32 into one VGPR of two RNE-rounded bf16
__device__ __forceinline__ unsigned pack_rne(float a, float b) {
  unsigned ua = __float_as_uint(a), ub = __float_as_uint(b);
  ua = ua + 0x7FFFu + ((ua >> 16) & 1u);
  ub = ub + 0x7FFFu + ((ub >> 16) & 1u);
  return (ua >> 16) | (ub & 0xFFFF0000u);
}
__device__ __forceinline__ void pack8(const float4& fa, const float4& fb,
                                      FragU& h) {
  h.u[0] = pack_rne(fa.x, fa.y);
  h.u[1] = pack_rne(fa.z, fa.w);
  h.u[2] = pack_rne(fb.x, fb.y);
  h.u[3] = pack_rne(fb.z, fb.w);
}

// ---------------- K1: projections via LDS-free bf16 MFMA -------------------
// grid 1536 = 384 row-tiles(16 rows) x 4 K-quarters. 4 waves/block, wave wv
// covers K [kq*512 + wv*128, +128), 4 steps of 32. ALL 24 float4 (W + x)
// prefetched to registers before any pack/MFMA -> single vmcnt drain.
__global__ __launch_bounds__(256, 2) void k1_proj(
    const float* __restrict__ x, const float* __restrict__ Wq,
    const float* __restrict__ Wk, const float* __restrict__ Wv,
    float* __restrict__ ws) {
  __shared__ float red[4][512];
  const int tid = threadIdx.x;
  const int lane = tid & 63, wv = tid >> 6;
  const int tile = blockIdx.x >> 2, kq = blockIdx.x & 3;
  const int m = tile >> 7, lr = (tile & 127) * 16;
  const float* W = (m == 0) ? Wq : (m == 1) ? Wk : Wv;

  const int kbase = kq * 512 + wv * 128 + (lane >> 4) * 8;
  const float* ap = W + (size_t)(lr + (lane & 15)) * D + kbase;
  const float* xp0 = x + (size_t)(lane & 15) * D + kbase;
  const float* xp1 = xp0 + 16 * D;

  float4 fa[4], fb[4], x0a[4], x0b[4], x1a[4], x1b[4];
#pragma unroll
  for (int s = 0; s < 4; ++s) {          // issue all 24 loads back-to-back
    const int off = s * 32;
    fa[s] = *(const float4*)(ap + off);
    fb[s] = *(const float4*)(ap + off + 4);
    x0a[s] = *(const float4*)(xp0 + off);
    x0b[s] = *(const float4*)(xp0 + off + 4);
    x1a[s] = *(const float4*)(xp1 + off);
    x1b[s] = *(const float4*)(xp1 + off + 4);
  }

  f32x4 acc0 = {0.f, 0.f, 0.f, 0.f}, acc1 = {0.f, 0.f, 0.f, 0.f};
#pragma unroll
  for (int s = 0; s < 4; ++s) {
    FragU Ah, Bh0, Bh1;
    pack8(fa[s], fb[s], Ah);
    pack8(x0a[s], x0b[s], Bh0);
    pack8(x1a[s], x1b[s], Bh1);
    acc0 = __builtin_amdgcn_mfma_f32_16x16x32_bf16(Ah.v, Bh0.v, acc0, 0, 0, 0);
    acc1 = __builtin_amdgcn_mfma_f32_16x16x32_bf16(Ah.v, Bh1.v, acc1, 0, 0, 0);
  }
  // C/D: col = lane&15 (batch), row = (lane>>4)*4 + reg (weight row)
  const int col = lane & 15, rq = (lane >> 4) * 4;
#pragma unroll
  for (int r = 0; r < 4; ++r) {
    red[wv][col * 16 + rq + r] = acc0[r];
    red[wv][(col + 16) * 16 + rq + r] = acc1[r];
  }
  __syncthreads();
  float* part = ws + (size_t)kq * PART_STRIDE + (size_t)m * 65536;
#pragma unroll
  for (int i = tid; i < 512; i += 256) {
    float s = (red[0][i] + red[1][i]) + (red[2][i] + red[3][i]);
    part[(size_t)(i >> 4) * D + lr + (i & 15)] = s;
  }
}

// ---------------- K2: finalize q/k/v once + q-minmax partials --------------
// grid 768 = 3 matrices x 32 batches x 8 chunks(256). One element/thread.
// m==0 blocks also reduce per-chunk q minmax and zero the partition
// counters (k3 depends on both; stream order guarantees visibility).
__global__ __launch_bounds__(256) void k2_fin(float* __restrict__ ws,
                                              const float* __restrict__ bq,
                                              const float* __restrict__ bk,
                                              const float* __restrict__ bv) {
  __shared__ float smx[4], smn[4];
  const int id = blockIdx.x, t = threadIdx.x;
  const int m = id >> 8, r = id & 255, b = r >> 3, c = r & 7;
  const int i = c * 256 + t;
  const size_t e = (size_t)m * 65536 + (size_t)b * D + i;
  float s = (ws[e] + ws[e + PART_STRIDE]) +
            (ws[e + 2 * PART_STRIDE] + ws[e + 3 * PART_STRIDE]);
  if (m == 0) {
    s += bq[i];
    ws[QF_OFF + (size_t)b * D + i] = s;
    float mx = s, mn = s;
#pragma unroll
    for (int off = 32; off; off >>= 1) {
      mx = fmaxf(mx, __shfl_down(mx, off));
      mn = fminf(mn, __shfl_down(mn, off));
    }
    if ((t & 63) == 0) { smx[t >> 6] = mx; smn[t >> 6] = mn; }
    __syncthreads();
    if (t == 0) {
      mx = fmaxf(fmaxf(smx[0], smx[1]), fmaxf(smx[2], smx[3]));
      mn = fminf(fminf(smn[0], smn[1]), fminf(smn[2], smn[3]));
      float* qm = ws + QMM_OFF + (size_t)(b * 8 + c) * 2;
      qm[0] = mx; qm[1] = mn;
    }
    if (c == 0 && t < 2) ((int*)(ws + CNT_OFF))[b * 2 + t] = 0;
  } else if (m == 1) {
    ws[KF_OFF + (size_t)b * D + i] = (s + bk[i]) * L2E;
  } else {
    ws[VF_OFF + (size_t)b * D + i] = s + bv[i];
  }
}

// ---------------- K3: Z + finalize d_j + two-ended partition ---------------
// grid 1024: b = bx>>5, jc = bx&31 (64 j). Thread t: j = jc*64+(t&63),
// i-eighth ih = t>>6 (256 i each). Stages final qf (8KB, one float4 load
// per thread) into LDS; hot loop reads via wave-uniform ds_read_b128
// broadcast (R11 form). 8-way LDS Z combine; t<64 appends (k2,d) to the
// per-batch two-ended stream via global atomic slot alloc (wave-agg).
__global__ __launch_bounds__(512, 8) void k3_z(
    const float* __restrict__ qf, const float* __restrict__ kf,
    const float* __restrict__ vf, const float* __restrict__ qmm,
    int* __restrict__ cnt, float2* __restrict__ pkd) {
  __shared__ float qs[2048];
  __shared__ float zs[512];
  const int bx = blockIdx.x, t = threadIdx.x;
  const int b = bx >> 5, jc = bx & 31;
  const size_t qb = (size_t)b * D;

  ((float4*)qs)[t] = ((const float4*)(qf + qb))[t];  // stage final q

  const float* qm = qmm + b * 16;
  float mx = qm[0], mn = qm[1];
#pragma unroll
  for (int w = 1; w < 8; ++w) {
    mx = fmaxf(mx, qm[2 * w]);
    mn = fminf(mn, qm[2 * w + 1]);
  }
  const int jl = t & 63, ih = t >> 6;
  const int j = jc * 64 + jl;
  const float k2 = kf[qb + j];
  const float m2 = (k2 >= 0.f) ? k2 * mx : k2 * mn;
  const float nm2 = -m2;
  __syncthreads();

  const float* qp = qs + ih * 256;
  float z0 = 0.f, z1 = 0.f, z2 = 0.f, z3 = 0.f;
#pragma unroll 8
  for (int i2 = 0; i2 < 256; i2 += 4) {
    float4 q4 = *(const float4*)&qp[i2];  // wave-uniform addr -> LDS broadcast
    z0 += fast_exp2(fmaf(q4.x, k2, nm2));
    z1 += fast_exp2(fmaf(q4.y, k2, nm2));
    z2 += fast_exp2(fmaf(q4.z, k2, nm2));
    z3 += fast_exp2(fmaf(q4.w, k2, nm2));
  }
  zs[t] = (z0 + z1) + (z2 + z3);
  __syncthreads();

  if (t < 64) {
    float Z = ((zs[t] + zs[t + 64]) + (zs[t + 128] + zs[t + 192])) +
              ((zs[t + 256] + zs[t + 320]) + (zs[t + 384] + zs[t + 448]));
    const float v = vf[qb + j];
    const float d = __log2f(fabsf(v) / Z) - m2;  // v==0 -> -inf -> 2^ -> 0
    float2* dst = pkd + qb;  // 2048 entries per batch
    if (v >= 0.f) {
      int s = atomicAdd(&cnt[b * 2], 1);
      dst[s] = make_float2(k2, d);
    } else {
      int s = atomicAdd(&cnt[b * 2 + 1], 1);
      dst[2047 - s] = make_float2(k2, d);
    }
  }
}

// ---------------- K4: out_i over the staged two-ended stream ---------------
// grid 1024: b = bx>>5, ic = bx&31 (64 i). Thread t: i = ic*64+(t&63),
// wave jh = t>>6 strides groups of 4 entries. Stages the whole per-batch
// stream (2048 float2 = 16KB) into LDS; hot loops are branch-free pos /
// neg over wave-uniform ds_read_b128 broadcasts; the single boundary
// group (pos/neg mix) is handled by one wave with per-element selects.
__global__ __launch_bounds__(512, 8) void k4_out(
    const float* __restrict__ qf, const int* __restrict__ cnt,
    const float2* __restrict__ pkd, float* __restrict__ out) {
  __shared__ float2 kd[2048];
  __shared__ float rs[512];
  const int bx = blockIdx.x, t = threadIdx.x;
  const int b = bx >> 5, ic = bx & 31;

  const float4* src = (const float4*)(pkd + (size_t)b * 2048);
  ((float4*)kd)[t] = src[t];
  ((float4*)kd)[t + 512] = src[t + 512];

  const int il = t & 63, jh = t >> 6;
  const int i = ic * 64 + il;
  const size_t io = (size_t)b * D + i;
  const float qi = qf[io];
  const int npos = cnt[b * 2];
  const int gb = npos >> 2;                       // boundary group
  const int gn = (gb + 1) + ((jh - gb - 1) & 7);  // first all-neg group, this wave
  __syncthreads();

  float p0 = 0.f, p1 = 0.f, p2 = 0.f, p3 = 0.f;
  float n0 = 0.f, n1 = 0.f, n2 = 0.f, n3 = 0.f;
  for (int g = jh; g < gb; g += 8) {              // all-pos groups
    const float4* e4 = (const float4*)kd + g * 2;
    float4 a = e4[0], c4 = e4[1];
    p0 += fast_exp2(fmaf(qi, a.x, a.y));
    p1 += fast_exp2(fmaf(qi, a.z, a.w));
    p2 += fast_exp2(fmaf(qi, c4.x, c4.y));
    p3 += fast_exp2(fmaf(qi, c4.z, c4.w));
  }
  if (jh == (gb & 7) && gb < 512) {               // boundary group: selects
    const float4* e4 = (const float4*)kd + gb * 2;
    float4 a = e4[0], c4 = e4[1];
    const int base = gb * 4;
    float e0 = fast_exp2(fmaf(qi, a.x, a.y));
    float e1 = fast_exp2(fmaf(qi, a.z, a.w));
    float e2 = fast_exp2(fmaf(qi, c4.x, c4.y));
    float e3 = fast_exp2(fmaf(qi, c4.z, c4.w));
    if (base + 0 < npos) p0 += e0; else n0 += e0;
    if (base + 1 < npos) p1 += e1; else n1 += e1;
    if (base + 2 < npos) p2 += e2; else n2 += e2;
    if (base + 3 < npos) p3 += e3; else n3 += e3;
  }
  for (int g = gn; g < 512; g += 8) {             // all-neg groups
    const float4* e4 = (const float4*)kd + g * 2;
    float4 a = e4[0], c4 = e4[1];
    n0 += fast_exp2(fmaf(qi, a.x, a.y));
    n1 += fast_exp2(fmaf(qi, a.z, a.w));
    n2 += fast_exp2(fmaf(qi, c4.x, c4.y));
    n3 += fast_exp2(fmaf(qi, c4.z, c4.w));
  }
  rs[t] = ((p0 + p1) + (p2 + p3)) - ((n0 + n1) + (n2 + n3));
  __syncthreads();
  if (t < 64)
    out[(size_t)b * D + ic * 64 + t] =
        ((rs[t] + rs[t + 64]) + (rs[t + 128] + rs[t + 192])) +
        ((rs[t + 256] + rs[t + 320]) + (rs[t + 384] + rs[t + 448]));
}

extern "C" void kernel_launch(void* const* d_in, const int* in_sizes, int n_in,
                              void* d_out, int out_size, void* d_ws, size_t ws_size,
                              hipStream_t stream) {
  (void)in_sizes; (void)n_in; (void)out_size; (void)ws_size;
  const float* x  = (const float*)d_in[0];
  const float* Wq = (const float*)d_in[1];
  const float* bq = (const float*)d_in[2];
  const float* Wk = (const float*)d_in[3];
  const float* bk = (const float*)d_in[4];
  const float* Wv = (const float*)d_in[5];
  const float* bv = (const float*)d_in[6];
  float* ws  = (float*)d_ws;
  float* out = (float*)d_out;

  k1_proj<<<1536, 256, 0, stream>>>(x, Wq, Wk, Wv, ws);
  k2_fin<<<768, 256, 0, stream>>>(ws, bq, bk, bv);
  k3_z<<<1024, 512, 0, stream>>>(ws + QF_OFF, ws + KF_OFF, ws + VF_OFF,
                                 ws + QMM_OFF, (int*)(ws + CNT_OFF),
                                 (float2*)(ws + PKD_OFF));
  k4_out<<<1024, 512, 0, stream>>>(ws + QF_OFF, (const int*)(ws + CNT_OFF),
                                   (const float2*)(ws + PKD_OFF), out);
}

// Round 3
// 140.194 us; speedup vs baseline: 3.8847x; 1.0533x over previous
//
#include <hip/hip_runtime.h>
#include <math.h>

// B=32, D=2048 rank-1 self-attention, fp32.
//   k2_j = k_j*log2e ; m2_j = k2_j>=0 ? k2_j*qmax : k2_j*qmin
//   Z_j  = sum_i 2^(q_i k2_j - m2_j) ; d_j = log2(|v_j|/Z_j) - m2_j
//   out_i = sum_{j:v>0} 2^(fma(q_i,k2_j,d_j)) - sum_{j:v<0} 2^(...)
//
// R14: ILP restructure. Post-mortem R13: k4's 6% work cut moved nothing and
// pure issue for 134M exp2 is ~10-14us/kernel (R12 calibration: VALUBusy*dur
// = 12.3us) while k3/k4 run ~35-40us -> latency-exposed dep chains, not
// issue-bound. Changes:
//  - k2_fin DROPPED (its 5us bought nothing; part re-reads are 3MB L2 hits).
//    k3/k4 re-sum parts in-kernel (R11-proven).
//  - k3: 2 j/thread (16-way i-split): 8 indep exp2 chains, LDS reads per
//    element halved. 2 broadcast addrs/wave = free (2-way, m136).
//  - partition: finalizers are exactly wave 0 -> __ballot + mbcnt prefix
//    gives two-ended slots in the block's OWN 64-entry segment. No atomics,
//    no global counters, no zero-init, no pads (2048 exact entries).
//  - k4: 2 i/thread, 128 i/block (grid 512): 16 indep chains, staging
//    amortized 2x, wave-uniform segment index, select-based boundary group.
// k1 unchanged (W-stream port-limited, ~8-12us).

#define D 2048
#define BATCH 32
#define NPART 4

// workspace float offsets
#define PART_STRIDE 196608   // one splitK part: 3*65536 (m*65536 + b*D + r)
#define PKD_OFF 786432       // float2[32][32][64]: per-(b,jc) two-ended segs
#define NPT_OFF 917504       // 1024 ints: npos per (b,jc)

#define L2E 1.4426950408889634f

typedef short s16x8 __attribute__((ext_vector_type(8)));
typedef float f32x4 __attribute__((ext_vector_type(4)));

union FragU { s16x8 v; unsigned u[4]; };

__device__ __forceinline__ float fast_exp2(float x) {
#if __has_builtin(__builtin_amdgcn_exp2f)
  return __builtin_amdgcn_exp2f(x);
#else
  return exp2f(x);
#endif
}
__device__ __forceinline__ int bits_below(unsigned long long m) {
  return __builtin_amdgcn_mbcnt_hi((unsigned)(m >> 32),
         __builtin_amdgcn_mbcnt_lo((unsigned)m, 0));
}
// pack two fp32 into one VGPR of two RNE-rounded bf16
__device__ __forceinline__ unsigned pack_rne(float a, float b) {
  unsigned ua = __float_as_uint(a), ub = __float_as_uint(b);
  ua = ua + 0x7FFFu + ((ua >> 16) & 1u);
  ub = ub + 0x7FFFu + ((ub >> 16) & 1u);
  return (ua >> 16) | (ub & 0xFFFF0000u);
}
__device__ __forceinline__ void pack8(const float4& fa, const float4& fb,
                                      FragU& h) {
  h.u[0] = pack_rne(fa.x, fa.y);
  h.u[1] = pack_rne(fa.z, fa.w);
  h.u[2] = pack_rne(fb.x, fb.y);
  h.u[3] = pack_rne(fb.z, fb.w);
}
// sum the 4 splitK partials at float offset o
__device__ __forceinline__ float sum_parts(const float* __restrict__ ws,
                                           size_t o) {
  float s0 = ws[o] + ws[o + PART_STRIDE];
  float s1 = ws[o + 2 * PART_STRIDE] + ws[o + 3 * PART_STRIDE];
  return s0 + s1;
}

// ---------------- K1: projections via LDS-free bf16 MFMA -------------------
// grid 1536 = 384 row-tiles(16 rows) x 4 K-quarters. 4 waves/block, wave wv
// covers K [kq*512 + wv*128, +128), 4 steps of 32. ALL 24 float4 (W + x)
// prefetched to registers before any pack/MFMA -> single vmcnt drain.
__global__ __launch_bounds__(256, 2) void k1_proj(
    const float* __restrict__ x, const float* __restrict__ Wq,
    const float* __restrict__ Wk, const float* __restrict__ Wv,
    float* __restrict__ ws) {
  __shared__ float red[4][512];
  const int tid = threadIdx.x;
  const int lane = tid & 63, wv = tid >> 6;
  const int tile = blockIdx.x >> 2, kq = blockIdx.x & 3;
  const int m = tile >> 7, lr = (tile & 127) * 16;
  const float* W = (m == 0) ? Wq : (m == 1) ? Wk : Wv;

  const int kbase = kq * 512 + wv * 128 + (lane >> 4) * 8;
  const float* ap = W + (size_t)(lr + (lane & 15)) * D + kbase;
  const float* xp0 = x + (size_t)(lane & 15) * D + kbase;
  const float* xp1 = xp0 + 16 * D;

  float4 fa[4], fb[4], x0a[4], x0b[4], x1a[4], x1b[4];
#pragma unroll
  for (int s = 0; s < 4; ++s) {          // issue all 24 loads back-to-back
    const int off = s * 32;
    fa[s] = *(const float4*)(ap + off);
    fb[s] = *(const float4*)(ap + off + 4);
    x0a[s] = *(const float4*)(xp0 + off);
    x0b[s] = *(const float4*)(xp0 + off + 4);
    x1a[s] = *(const float4*)(xp1 + off);
    x1b[s] = *(const float4*)(xp1 + off + 4);
  }

  f32x4 acc0 = {0.f, 0.f, 0.f, 0.f}, acc1 = {0.f, 0.f, 0.f, 0.f};
#pragma unroll
  for (int s = 0; s < 4; ++s) {
    FragU Ah, Bh0, Bh1;
    pack8(fa[s], fb[s], Ah);
    pack8(x0a[s], x0b[s], Bh0);
    pack8(x1a[s], x1b[s], Bh1);
    acc0 = __builtin_amdgcn_mfma_f32_16x16x32_bf16(Ah.v, Bh0.v, acc0, 0, 0, 0);
    acc1 = __builtin_amdgcn_mfma_f32_16x16x32_bf16(Ah.v, Bh1.v, acc1, 0, 0, 0);
  }
  // C/D: col = lane&15 (batch), row = (lane>>4)*4 + reg (weight row)
  const int col = lane & 15, rq = (lane >> 4) * 4;
#pragma unroll
  for (int r = 0; r < 4; ++r) {
    red[wv][col * 16 + rq + r] = acc0[r];
    red[wv][(col + 16) * 16 + rq + r] = acc1[r];
  }
  __syncthreads();
  float* part = ws + (size_t)kq * PART_STRIDE + (size_t)m * 65536;
#pragma unroll
  for (int i = tid; i < 512; i += 256) {
    float s = (red[0][i] + red[1][i]) + (red[2][i] + red[3][i]);
    part[(size_t)(i >> 4) * D + lr + (i & 15)] = s;
  }
}

// ---------------- K3: Z + finalize d_j + ballot partition ------------------
// grid 1024: b = bx>>5, jc = bx&31 (64 j per block). Thread t: TWO j's
// (j0 = jc*64 + (t&31), j1 = j0+32), i-sixteenth ih = t>>5 (128 i each).
// Stages q (= sum parts + bq) in LDS with in-flight minmax; hot loop has 8
// independent fma->exp2->add chains per thread reading wave-2-addr LDS
// broadcasts. 16-way transposed zs combine; wave 0 finalizes d_j and
// writes the block's own 64-entry two-ended segment via ballot prefix.
__global__ __launch_bounds__(512, 8) void k3_z(float* __restrict__ ws,
                                               const float* __restrict__ bq,
                                               const float* __restrict__ bk,
                                               const float* __restrict__ bv) {
  __shared__ float qs[2048];
  __shared__ float zs[1024];
  __shared__ float ks2[64], ms2[64];
  __shared__ float rmx[8], rmn[8];
  const int bx = blockIdx.x, t = threadIdx.x;
  const int b = bx >> 5, jc = bx & 31;
  const size_t qb = (size_t)b * D;

  // stage q = sum of 4 parts + bq (4 floats/thread) + minmax
  float4 p0 = ((const float4*)(ws + qb))[t];
  float4 p1 = ((const float4*)(ws + PART_STRIDE + qb))[t];
  float4 p2 = ((const float4*)(ws + 2 * PART_STRIDE + qb))[t];
  float4 p3 = ((const float4*)(ws + 3 * PART_STRIDE + qb))[t];
  float4 bb = ((const float4*)bq)[t];
  float4 qv = {(p0.x + p1.x) + (p2.x + p3.x) + bb.x,
               (p0.y + p1.y) + (p2.y + p3.y) + bb.y,
               (p0.z + p1.z) + (p2.z + p3.z) + bb.z,
               (p0.w + p1.w) + (p2.w + p3.w) + bb.w};
  *(float4*)&qs[t * 4] = qv;
  float mx = fmaxf(fmaxf(qv.x, qv.y), fmaxf(qv.z, qv.w));
  float mn = fminf(fminf(qv.x, qv.y), fminf(qv.z, qv.w));
#pragma unroll
  for (int off = 32; off; off >>= 1) {
    mx = fmaxf(mx, __shfl_down(mx, off));
    mn = fminf(mn, __shfl_down(mn, off));
  }
  if ((t & 63) == 0) { rmx[t >> 6] = mx; rmn[t >> 6] = mn; }
  __syncthreads();
  mx = rmx[0]; mn = rmn[0];
#pragma unroll
  for (int w = 1; w < 8; ++w) {
    mx = fmaxf(mx, rmx[w]);
    mn = fminf(mn, rmn[w]);
  }

  const int jp = t & 31, ih = t >> 5;
  const int j0 = jc * 64 + jp, j1 = j0 + 32;
  const float k2a = (sum_parts(ws, 65536 + qb + j0) + bk[j0]) * L2E;
  const float k2b = (sum_parts(ws, 65536 + qb + j1) + bk[j1]) * L2E;
  const float m2a = (k2a >= 0.f) ? k2a * mx : k2a * mn;
  const float m2b = (k2b >= 0.f) ? k2b * mx : k2b * mn;
  if (ih == 0) {                       // stash for wave-0 finalize
    ks2[jp] = k2a; ks2[32 + jp] = k2b;
    ms2[jp] = m2a; ms2[32 + jp] = m2b;
  }
  const float na = -m2a, nb = -m2b;
  const float* qp = qs + ih * 128;
  float za0 = 0.f, za1 = 0.f, za2 = 0.f, za3 = 0.f;
  float zb0 = 0.f, zb1 = 0.f, zb2 = 0.f, zb3 = 0.f;
#pragma unroll 8
  for (int i2 = 0; i2 < 128; i2 += 4) {
    float4 q4 = *(const float4*)&qp[i2];  // 2 addrs/wave -> free broadcast
    za0 += fast_exp2(fmaf(q4.x, k2a, na));
    za1 += fast_exp2(fmaf(q4.y, k2a, na));
    za2 += fast_exp2(fmaf(q4.z, k2a, na));
    za3 += fast_exp2(fmaf(q4.w, k2a, na));
    zb0 += fast_exp2(fmaf(q4.x, k2b, nb));
    zb1 += fast_exp2(fmaf(q4.y, k2b, nb));
    zb2 += fast_exp2(fmaf(q4.z, k2b, nb));
    zb3 += fast_exp2(fmaf(q4.w, k2b, nb));
  }
  zs[ih * 64 + jp]      = (za0 + za1) + (za2 + za3);   // transposed [ih][jl]
  zs[ih * 64 + 32 + jp] = (zb0 + zb1) + (zb2 + zb3);
  __syncthreads();

  if (t < 64) {                        // exactly wave 0
    float Z = 0.f;
#pragma unroll
    for (int h = 0; h < 16; ++h) Z += zs[h * 64 + t];  // conflict-free cols
    const int j = jc * 64 + t;
    const float v = sum_parts(ws, 131072 + qb + j) + bv[j];
    const float d = __log2f(fabsf(v) / Z) - ms2[t];  // v==0 -> -inf -> 2^ -> 0
    const unsigned long long msk = __ballot(v >= 0.f);
    const int npos = __popcll(msk);
    const int slot = (v >= 0.f) ? bits_below(msk) : 63 - bits_below(~msk);
    float2* dst = (float2*)(ws + PKD_OFF) + ((size_t)b * 32 + jc) * 64;
    dst[slot] = make_float2(ks2[t], d);
    if (t == 0) ((int*)(ws + NPT_OFF))[b * 32 + jc] = npos;
  }
}

// ---------------- K4: out_i over the staged segments, 2 i/thread -----------
// grid 512: b = bx>>4, ic = bx&15 (128 i per block). Thread t: i0 = ic*128 +
// (t&63), i1 = i0+64 (16 indep chains), wave jh = t>>6 covers 4 segments of
// 64 entries (wave-uniform LDS broadcast). Boundary group per segment via
// per-element selects (no pads). rs padded [128][9] to dodge bank conflicts.
__global__ __launch_bounds__(512, 4) void k4_out(const float* __restrict__ ws,
                                                 const float* __restrict__ bq,
                                                 float* __restrict__ out) {
  __shared__ float2 kd[2048];
  __shared__ int np[32];
  __shared__ float rs[128 * 9];
  const int bx = blockIdx.x, t = threadIdx.x;
  const int b = bx >> 4, ic = bx & 15;
  const size_t qb = (size_t)b * D;

  const float4* src = (const float4*)((const float2*)(ws + PKD_OFF) +
                                      (size_t)b * 2048);
  ((float4*)kd)[t] = src[t];
  ((float4*)kd)[t + 512] = src[t + 512];
  if (t < 32) np[t] = ((const int*)(ws + NPT_OFF))[b * 32 + t];

  const int il = t & 63, jh = t >> 6;
  const int i0 = ic * 128 + il, i1 = i0 + 64;
  const float qi0 = sum_parts(ws, qb + i0) + bq[i0];
  const float qi1 = sum_parts(ws, qb + i1) + bq[i1];
  __syncthreads();

  float pa0 = 0.f, pa1 = 0.f, pa2 = 0.f, pa3 = 0.f;
  float pb0 = 0.f, pb1 = 0.f, pb2 = 0.f, pb3 = 0.f;
  float na0 = 0.f, na1 = 0.f, na2 = 0.f, na3 = 0.f;
  float nb0 = 0.f, nb1 = 0.f, nb2 = 0.f, nb3 = 0.f;
#pragma unroll
  for (int s4 = 0; s4 < 4; ++s4) {
    const int s = jh * 4 + s4;
    const float4* seg = (const float4*)(kd + s * 64);
    const int npos = np[s], gb = npos >> 2;
    for (int g = 0; g < gb; ++g) {            // all-pos groups
      float4 a = seg[g * 2], c = seg[g * 2 + 1];
      pa0 += fast_exp2(fmaf(qi0, a.x, a.y));
      pa1 += fast_exp2(fmaf(qi0, a.z, a.w));
      pa2 += fast_exp2(fmaf(qi0, c.x, c.y));
      pa3 += fast_exp2(fmaf(qi0, c.z, c.w));
      pb0 += fast_exp2(fmaf(qi1, a.x, a.y));
      pb1 += fast_exp2(fmaf(qi1, a.z, a.w));
      pb2 += fast_exp2(fmaf(qi1, c.x, c.y));
      pb3 += fast_exp2(fmaf(qi1, c.z, c.w));
    }
    if (gb < 16) {
      {                                        // boundary group: selects
        float4 a = seg[gb * 2], c = seg[gb * 2 + 1];
        const int base = gb * 4;
        float ea0 = fast_exp2(fmaf(qi0, a.x, a.y));
        float ea1 = fast_exp2(fmaf(qi0, a.z, a.w));
        float ea2 = fast_exp2(fmaf(qi0, c.x, c.y));
        float ea3 = fast_exp2(fmaf(qi0, c.z, c.w));
        float eb0 = fast_exp2(fmaf(qi1, a.x, a.y));
        float eb1 = fast_exp2(fmaf(qi1, a.z, a.w));
        float eb2 = fast_exp2(fmaf(qi1, c.x, c.y));
        float eb3 = fast_exp2(fmaf(qi1, c.z, c.w));
        if (base + 0 < npos) { pa0 += ea0; pb0 += eb0; }
        else                 { na0 += ea0; nb0 += eb0; }
        if (base + 1 < npos) { pa1 += ea1; pb1 += eb1; }
        else                 { na1 += ea1; nb1 += eb1; }
        if (base + 2 < npos) { pa2 += ea2; pb2 += eb2; }
        else                 { na2 += ea2; nb2 += eb2; }
        if (base + 3 < npos) { pa3 += ea3; pb3 += eb3; }
        else                 { na3 += ea3; nb3 += eb3; }
      }
      for (int g = gb + 1; g < 16; ++g) {     // all-neg groups
        float4 a = seg[g * 2], c = seg[g * 2 + 1];
        na0 += fast_exp2(fmaf(qi0, a.x, a.y));
        na1 += fast_exp2(fmaf(qi0, a.z, a.w));
        na2 += fast_exp2(fmaf(qi0, c.x, c.y));
        na3 += fast_exp2(fmaf(qi0, c.z, c.w));
        nb0 += fast_exp2(fmaf(qi1, a.x, a.y));
        nb1 += fast_exp2(fmaf(qi1, a.z, a.w));
        nb2 += fast_exp2(fmaf(qi1, c.x, c.y));
        nb3 += fast_exp2(fmaf(qi1, c.z, c.w));
      }
    }
  }
  rs[il * 9 + jh] = ((pa0 + pa1) + (pa2 + pa3)) - ((na0 + na1) + (na2 + na3));
  rs[(64 + il) * 9 + jh] =
      ((pb0 + pb1) + (pb2 + pb3)) - ((nb0 + nb1) + (nb2 + nb3));
  __syncthreads();
  if (t < 128) {
    float s = 0.f;
#pragma unroll
    for (int h = 0; h < 8; ++h) s += rs[t * 9 + h];
    out[qb + ic * 128 + t] = s;
  }
}

extern "C" void kernel_launch(void* const* d_in, const int* in_sizes, int n_in,
                              void* d_out, int out_size, void* d_ws, size_t ws_size,
                              hipStream_t stream) {
  (void)in_sizes; (void)n_in; (void)out_size; (void)ws_size;
  const float* x  = (const float*)d_in[0];
  const float* Wq = (const float*)d_in[1];
  const float* bq = (const float*)d_in[2];
  const float* Wk = (const float*)d_in[3];
  const float* bk = (const float*)d_in[4];
  const float* Wv = (const float*)d_in[5];
  const float* bv = (const float*)d_in[6];
  float* ws  = (float*)d_ws;
  float* out = (float*)d_out;

  k1_proj<<<1536, 256, 0, stream>>>(x, Wq, Wk, Wv, ws);
  k3_z<<<1024, 512, 0, stream>>>(ws, bq, bk, bv);
  k4_out<<<512, 512, 0, stream>>>(ws, bq, out);
}

// Round 4
// 136.521 us; speedup vs baseline: 3.9892x; 1.0269x over previous
//
#include <hip/hip_runtime.h>
#include <math.h>

// B=32, D=2048 rank-1 self-attention, fp32.
//   k2_j = k_j*log2e ; m2_j = k2_j>=0 ? k2_j*qmax : k2_j*qmin
//   Z_j  = sum_i 2^(q_i k2_j - m2_j) ; d_j = log2(|v_j|/Z_j) - m2_j
//   out_i = sum_{j:v>0} 2^(fma(q_i,k2_j,d_j)) - sum_{j:v<0} 2^(...)
//
// R15: provably-safe term pruning. R14 post-mortem: k3+k4 ~80us vs ~26us
// VALU floor; three scheduling restructures were neutral -> cut the term
// COUNT, not the cost per term.
//  - Z terms with q_i k2 - m2 < -40 are < 2^-40 of the guaranteed max term
//    (=1, always in-window): skipped mass <= 2048*2^-40 ~ 2e-9 rel.
//  - out terms with upper-bound k2 q_i + d < -28: skipped <= 8e-6 abs
//    (current absmax 2.5 from bf16 k1).
//  - k0_prep value-buckets q and k2 (64 ascending buckets + offsets +
//    orig indices). Windows = suffix/prefix of bucketed-q, O(1) start.
//  - k3: wave lanes = 32 consecutive bucketed-k2 j (coherent windows);
//    16-way i-split; 2048 blocks, central(full-window) groups dispatched
//    first, 2x oversubscribed for balance. Emits per-seg (k2mn,k2mx,dmx).
//  - k4: wave lanes = 32 consecutive bucketed-q i (coherent skip); per-seg
//    skip via smeta upper bound; scatter out by orig index; extreme-q
//    blocks first.
// k1 unchanged (~10us). No global atomics, nothing pre-zeroed.

#define D 2048
#define BATCH 32

// workspace float offsets
#define PART_STRIDE 196608   // one splitK part: 3*65536 (m*65536 + b*D + r)
#define BQV_OFF   786432     // bucketed q values [32][2048]
#define BQI_OFF   851968     // bucketed q orig index (int) [32][2048]
#define BK2_OFF   917504     // bucketed k2 values [32][2048]
#define BKI_OFF   983040     // bucketed k2 orig index (int) [32][2048]
#define META_OFF  1048576    // per b (stride 80): [0]qmx [1]qmn [2]scale, int off[65] at +8
#define PKD_OFF   1051136    // float2[32][64][32] two-ended segs (pos up, neg down)
#define NPT_OFF   1182208    // int[32][64] npos per seg
#define SMETA_OFF 1184256    // float4[32][64]: k2min,k2max,dmax per seg

#define L2E 1.4426950408889634f

typedef short s16x8 __attribute__((ext_vector_type(8)));
typedef float f32x4 __attribute__((ext_vector_type(4)));

union FragU { s16x8 v; unsigned u[4]; };

__device__ __forceinline__ float fast_exp2(float x) {
#if __has_builtin(__builtin_amdgcn_exp2f)
  return __builtin_amdgcn_exp2f(x);
#else
  return exp2f(x);
#endif
}
__device__ __forceinline__ int bits_below(unsigned long long m) {
  return __builtin_amdgcn_mbcnt_hi((unsigned)(m >> 32),
         __builtin_amdgcn_mbcnt_lo((unsigned)m, 0));
}
__device__ __forceinline__ unsigned pack_rne(float a, float b) {
  unsigned ua = __float_as_uint(a), ub = __float_as_uint(b);
  ua = ua + 0x7FFFu + ((ua >> 16) & 1u);
  ub = ub + 0x7FFFu + ((ub >> 16) & 1u);
  return (ua >> 16) | (ub & 0xFFFF0000u);
}
__device__ __forceinline__ void pack8(const float4& fa, const float4& fb,
                                      FragU& h) {
  h.u[0] = pack_rne(fa.x, fa.y);
  h.u[1] = pack_rne(fa.z, fa.w);
  h.u[2] = pack_rne(fb.x, fb.y);
  h.u[3] = pack_rne(fb.z, fb.w);
}
__device__ __forceinline__ float sum_parts(const float* __restrict__ ws,
                                           size_t o) {
  float s0 = ws[o] + ws[o + PART_STRIDE];
  float s1 = ws[o + 2 * PART_STRIDE] + ws[o + 3 * PART_STRIDE];
  return s0 + s1;
}

// ---------------- K1: projections via LDS-free bf16 MFMA -------------------
__global__ __launch_bounds__(256, 2) void k1_proj(
    const float* __restrict__ x, const float* __restrict__ Wq,
    const float* __restrict__ Wk, const float* __restrict__ Wv,
    float* __restrict__ ws) {
  __shared__ float red[4][512];
  const int tid = threadIdx.x;
  const int lane = tid & 63, wv = tid >> 6;
  const int tile = blockIdx.x >> 2, kq = blockIdx.x & 3;
  const int m = tile >> 7, lr = (tile & 127) * 16;
  const float* W = (m == 0) ? Wq : (m == 1) ? Wk : Wv;

  const int kbase = kq * 512 + wv * 128 + (lane >> 4) * 8;
  const float* ap = W + (size_t)(lr + (lane & 15)) * D + kbase;
  const float* xp0 = x + (size_t)(lane & 15) * D + kbase;
  const float* xp1 = xp0 + 16 * D;

  float4 fa[4], fb[4], x0a[4], x0b[4], x1a[4], x1b[4];
#pragma unroll
  for (int s = 0; s < 4; ++s) {
    const int off = s * 32;
    fa[s] = *(const float4*)(ap + off);
    fb[s] = *(const float4*)(ap + off + 4);
    x0a[s] = *(const float4*)(xp0 + off);
    x0b[s] = *(const float4*)(xp0 + off + 4);
    x1a[s] = *(const float4*)(xp1 + off);
    x1b[s] = *(const float4*)(xp1 + off + 4);
  }

  f32x4 acc0 = {0.f, 0.f, 0.f, 0.f}, acc1 = {0.f, 0.f, 0.f, 0.f};
#pragma unroll
  for (int s = 0; s < 4; ++s) {
    FragU Ah, Bh0, Bh1;
    pack8(fa[s], fb[s], Ah);
    pack8(x0a[s], x0b[s], Bh0);
    pack8(x1a[s], x1b[s], Bh1);
    acc0 = __builtin_amdgcn_mfma_f32_16x16x32_bf16(Ah.v, Bh0.v, acc0, 0, 0, 0);
    acc1 = __builtin_amdgcn_mfma_f32_16x16x32_bf16(Ah.v, Bh1.v, acc1, 0, 0, 0);
  }
  const int col = lane & 15, rq = (lane >> 4) * 4;
#pragma unroll
  for (int r = 0; r < 4; ++r) {
    red[wv][col * 16 + rq + r] = acc0[r];
    red[wv][(col + 16) * 16 + rq + r] = acc1[r];
  }
  __syncthreads();
  float* part = ws + (size_t)kq * PART_STRIDE + (size_t)m * 65536;
#pragma unroll
  for (int i = tid; i < 512; i += 256) {
    float s = (red[0][i] + red[1][i]) + (red[2][i] + red[3][i]);
    part[(size_t)(i >> 4) * D + lr + (i & 15)] = s;
  }
}

// ---------------- K0: bucketize q (pass 0) and k2 (pass 1) ----------------
// grid 64: b = bx&31, pass = bx>>5. 512 threads, 4 elements each. Value
// buckets (64, ascending), LDS-atomic counts, serial prefix, scatter with
// orig index. q pass also writes meta {qmx,qmn,scale,off[65]}.
__global__ __launch_bounds__(512) void k0_prep(float* __restrict__ ws,
                                               const float* __restrict__ bq,
                                               const float* __restrict__ bk) {
  __shared__ int cnt[64], off[65], cur[64];
  __shared__ float rmx[8], rmn[8];
  const int bx = blockIdx.x, t = threadIdx.x;
  const int b = bx & 31, pass = bx >> 5;
  const size_t qb = (size_t)b * D;
  float* meta = ws + META_OFF + b * 80;

  const size_t src = (pass ? 65536 : 0) + qb;
  float4 p0 = ((const float4*)(ws + src))[t];
  float4 p1 = ((const float4*)(ws + PART_STRIDE + src))[t];
  float4 p2 = ((const float4*)(ws + 2 * PART_STRIDE + src))[t];
  float4 p3 = ((const float4*)(ws + 3 * PART_STRIDE + src))[t];
  float4 bb = pass ? ((const float4*)bk)[t] : ((const float4*)bq)[t];
  float4 qv = {(p0.x + p1.x) + (p2.x + p3.x) + bb.x,
               (p0.y + p1.y) + (p2.y + p3.y) + bb.y,
               (p0.z + p1.z) + (p2.z + p3.z) + bb.z,
               (p0.w + p1.w) + (p2.w + p3.w) + bb.w};
  if (pass) {                       // k2 = (k + bk) * log2e
    qv.x *= L2E; qv.y *= L2E; qv.z *= L2E; qv.w *= L2E;
  }
  float mx = fmaxf(fmaxf(qv.x, qv.y), fmaxf(qv.z, qv.w));
  float mn = fminf(fminf(qv.x, qv.y), fminf(qv.z, qv.w));
#pragma unroll
  for (int o = 32; o; o >>= 1) {
    mx = fmaxf(mx, __shfl_down(mx, o));
    mn = fminf(mn, __shfl_down(mn, o));
  }
  if ((t & 63) == 0) { rmx[t >> 6] = mx; rmn[t >> 6] = mn; }
  if (t < 64) cnt[t] = 0;
  __syncthreads();
  mx = rmx[0]; mn = rmn[0];
#pragma unroll
  for (int w = 1; w < 8; ++w) {
    mx = fmaxf(mx, rmx[w]);
    mn = fminf(mn, rmn[w]);
  }
  const float scale = (mx > mn) ? 64.0f / (mx - mn) : 0.f;
  float vals[4] = {qv.x, qv.y, qv.z, qv.w};
  int bi[4];
#pragma unroll
  for (int e = 0; e < 4; ++e) {
    bi[e] = (int)fminf(63.f, fmaxf(0.f, (vals[e] - mn) * scale));
    atomicAdd(&cnt[bi[e]], 1);
  }
  __syncthreads();
  if (t == 0) {
    int a = 0;
#pragma unroll
    for (int i = 0; i < 64; ++i) { off[i] = a; cur[i] = a; a += cnt[i]; }
    off[64] = a;
  }
  __syncthreads();
  const size_t vdst = (pass ? BK2_OFF : BQV_OFF) + qb;
  const size_t idst = (pass ? BKI_OFF : BQI_OFF) + qb;
#pragma unroll
  for (int e = 0; e < 4; ++e) {
    const int pos = atomicAdd(&cur[bi[e]], 1);
    ws[vdst + pos] = vals[e];
    ((int*)ws)[idst + pos] = t * 4 + e;
  }
  if (pass == 0) {
    if (t == 0) { meta[0] = mx; meta[1] = mn; meta[2] = scale; }
    if (t < 65) ((int*)meta)[8 + t] = off[t];
  }
}

// ---------------- K3: windowed Z + finalize d + partition + seg meta -------
// grid 2048: b = bx&31, group g (32 bucketed-k2 j's) LPT-ordered (central
// full-window groups first). 512 thr = 32 j x 16 i-splits of each j's own
// window (suffix for k2>0, prefix for k2<0, in bucketed-q order). t<32
// finalizes, ballot-partitions the two-ended 32-seg, reduces seg meta.
__global__ __launch_bounds__(512, 8) void k3_z(float* __restrict__ ws,
                                               const float* __restrict__ bv) {
  __shared__ float qs[2048];
  __shared__ float zs[512];
  __shared__ int ob[65];
  const int bx = blockIdx.x, t = threadIdx.x;
  const int b = bx & 31, s = bx >> 5;
  const int g = (s & 1) ? 32 + (s >> 1) : 31 - (s >> 1);  // 31,32,30,33,...
  const size_t qb = (size_t)b * D;
  const float* meta = ws + META_OFF + b * 80;

  ((float4*)qs)[t] = ((const float4*)(ws + BQV_OFF + qb))[t];
  if (t < 65) ob[t] = ((const int*)meta)[8 + t];
  const float qmx = meta[0], qmn = meta[1], scale = meta[2];

  const int jl = t & 31, ih = t >> 5;
  const int p = g * 32 + jl;                 // bucketed j position
  const float k2 = ws[BK2_OFF + qb + p];
  const int oj = ((const int*)ws)[BKI_OFF + qb + p];
  const float m2 = (k2 >= 0.f) ? k2 * qmx : k2 * qmn;
  const float nm2 = -m2;
  __syncthreads();

  int st, en;
  if (k2 >= 0.f) {                 // keep q >= qmx - 40/k2  (suffix)
    const float c = qmx - 40.f / k2;        // k2==0 -> -inf -> full
    const int B = (int)fminf(63.f, fmaxf(0.f, (c - qmn) * scale));
    st = ob[B] & ~3; en = 2048;
  } else {                         // keep q <= qmn + 40/|k2| (prefix)
    const float c = qmn + 40.f / (-k2);
    const int B = (int)fminf(63.f, fmaxf(0.f, (c - qmn) * scale));
    st = 0; en = (ob[B + 1] + 3) & ~3;
  }
  const int nq = (en - st) >> 2;
  const int i0 = st + (((nq * ih) >> 4) << 2);
  const int i1 = st + (((nq * (ih + 1)) >> 4) << 2);
  float z0 = 0.f, z1 = 0.f, z2 = 0.f, z3 = 0.f;
  for (int idx = i0; idx < i1; idx += 4) {
    float4 q4 = *(const float4*)&qs[idx];
    z0 += fast_exp2(fmaf(q4.x, k2, nm2));
    z1 += fast_exp2(fmaf(q4.y, k2, nm2));
    z2 += fast_exp2(fmaf(q4.z, k2, nm2));
    z3 += fast_exp2(fmaf(q4.w, k2, nm2));
  }
  zs[ih * 32 + jl] = (z0 + z1) + (z2 + z3);
  __syncthreads();

  if (t < 32) {                              // wave 0, lanes 0-31
    float Z = 0.f;
#pragma unroll
    for (int h = 0; h < 16; ++h) Z += zs[h * 32 + t];
    const float v = sum_parts(ws, 131072 + qb + oj) + bv[oj];
    const float d = __log2f(fabsf(v) / Z) - m2;  // v==0 -> -inf -> 2^ -> 0
    const unsigned long long msk = __ballot(v >= 0.f);
    const int npos = __popcll(msk);
    const int slot = (v >= 0.f) ? bits_below(msk)
                                : 31 - bits_below(~msk & 0xFFFFFFFFull);
    float2* dst = (float2*)(ws + PKD_OFF) + ((size_t)b * 64 + g) * 32;
    dst[slot] = make_float2(k2, d);
    if (t == 0) ((int*)(ws + NPT_OFF))[b * 64 + g] = npos;
    float kmn = k2, kmx = k2, dmx = d;       // seg meta over 32 lanes
#pragma unroll
    for (int o = 16; o; o >>= 1) {
      kmn = fminf(kmn, __shfl_down(kmn, o, 32));
      kmx = fmaxf(kmx, __shfl_down(kmx, o, 32));
      dmx = fmaxf(dmx, __shfl_down(dmx, o, 32));
    }
    if (t == 0)
      ((float4*)(ws + SMETA_OFF))[b * 64 + g] =
          make_float4(kmn, kmx, dmx, 0.f);
  }
}

// ---------------- K4: out over segs with upper-bound skip ------------------
// grid 2048: b = bx&31, ic LPT-ordered (extreme-q blocks first). 512 thr =
// 32 bucketed-q i x 16 seg-quarters (4 segs of 32 each). Per-seg skip when
// max(k2mn*qi, k2mx*qi)+dmx < -28 (lanes = similar q -> coherent). Output
// scattered to orig i.
__global__ __launch_bounds__(512, 8) void k4_out(const float* __restrict__ ws,
                                                 float* __restrict__ out) {
  __shared__ float2 kd[2048];
  __shared__ float4 sm[64];
  __shared__ int np[64];
  __shared__ float rs[32 * 17];
  const int bx = blockIdx.x, t = threadIdx.x;
  const int b = bx & 31, s = bx >> 5;
  const int ic = (s & 1) ? 63 - (s >> 1) : (s >> 1);   // 0,63,1,62,...
  const size_t qb = (size_t)b * D;

  const float4* src = (const float4*)((const float2*)(ws + PKD_OFF) +
                                      (size_t)b * 2048);
  ((float4*)kd)[t] = src[t];
  ((float4*)kd)[t + 512] = src[t + 512];
  if (t < 64) {
    np[t] = ((const int*)(ws + NPT_OFF))[b * 64 + t];
    sm[t] = ((const float4*)(ws + SMETA_OFF))[b * 64 + t];
  }
  const int il = t & 31, jh = t >> 5;
  const int pos = ic * 32 + il;              // bucketed q position
  const float qi = ws[BQV_OFF + qb + pos];
  const int oi = ((const int*)ws)[BQI_OFF + qb + pos];
  __syncthreads();

  float p0 = 0.f, p1 = 0.f, p2 = 0.f, p3 = 0.f;
  float n0 = 0.f, n1 = 0.f, n2 = 0.f, n3 = 0.f;
#pragma unroll
  for (int s4 = 0; s4 < 4; ++s4) {
    const int sg = jh * 4 + s4;
    const float4 m = sm[sg];
    const float ub = fmaxf(m.x * qi, m.y * qi) + m.z;
    if (ub < -28.f) continue;                // whole seg < 2^-28: skip
    const float4* seg = (const float4*)(kd + sg * 32);
    const int npos = np[sg], gb = npos >> 2;
    for (int gq = 0; gq < gb; ++gq) {        // all-pos quads
      float4 a = seg[gq * 2], c = seg[gq * 2 + 1];
      p0 += fast_exp2(fmaf(qi, a.x, a.y));
      p1 += fast_exp2(fmaf(qi, a.z, a.w));
      p2 += fast_exp2(fmaf(qi, c.x, c.y));
      p3 += fast_exp2(fmaf(qi, c.z, c.w));
    }
    if (gb < 8) {
      {                                      // boundary quad: selects
        float4 a = seg[gb * 2], c = seg[gb * 2 + 1];
        const int base = gb * 4;
        float e0 = fast_exp2(fmaf(qi, a.x, a.y));
        float e1 = fast_exp2(fmaf(qi, a.z, a.w));
        float e2 = fast_exp2(fmaf(qi, c.x, c.y));
        float e3 = fast_exp2(fmaf(qi, c.z, c.w));
        if (base + 0 < npos) p0 += e0; else n0 += e0;
        if (base + 1 < npos) p1 += e1; else n1 += e1;
        if (base + 2 < npos) p2 += e2; else n2 += e2;
        if (base + 3 < npos) p3 += e3; else n3 += e3;
      }
      for (int gq = gb + 1; gq < 8; ++gq) {  // all-neg quads
        float4 a = seg[gq * 2], c = seg[gq * 2 + 1];
        n0 += fast_exp2(fmaf(qi, a.x, a.y));
        n1 += fast_exp2(fmaf(qi, a.z, a.w));
        n2 += fast_exp2(fmaf(qi, c.x, c.y));
        n3 += fast_exp2(fmaf(qi, c.z, c.w));
      }
    }
  }
  rs[il * 17 + jh] = ((p0 + p1) + (p2 + p3)) - ((n0 + n1) + (n2 + n3));
  __syncthreads();
  if (t < 32) {
    float sum = 0.f;
#pragma unroll
    for (int h = 0; h < 16; ++h) sum += rs[t * 17 + h];
    out[qb + oi] = sum;                      // scatter to orig i
  }
}

extern "C" void kernel_launch(void* const* d_in, const int* in_sizes, int n_in,
                              void* d_out, int out_size, void* d_ws, size_t ws_size,
                              hipStream_t stream) {
  (void)in_sizes; (void)n_in; (void)out_size; (void)ws_size;
  const float* x  = (const float*)d_in[0];
  const float* Wq = (const float*)d_in[1];
  const float* bq = (const float*)d_in[2];
  const float* Wk = (const float*)d_in[3];
  const float* bk = (const float*)d_in[4];
  const float* Wv = (const float*)d_in[5];
  const float* bv = (const float*)d_in[6];
  float* ws  = (float*)d_ws;
  float* out = (float*)d_out;

  k1_proj<<<1536, 256, 0, stream>>>(x, Wq, Wk, Wv, ws);
  k0_prep<<<64, 512, 0, stream>>>(ws, bq, bk);
  k3_z<<<2048, 512, 0, stream>>>(ws, bv);
  k4_out<<<2048, 512, 0, stream>>>(ws, out);
}

// Round 5
// 134.393 us; speedup vs baseline: 4.0524x; 1.0158x over previous
//
#include <hip/hip_runtime.h>
#include <math.h>

// B=32, D=2048 rank-1 self-attention, fp32.
//   k2_j = k_j*log2e ; m2_j = k2_j>=0 ? k2_j*qmax : k2_j*qmin
//   Z_j  = sum_i 2^(q_i k2_j - m2_j) ; d_j = log2(|v_j|/Z_j) - m2_j
//   out_i = sum_{j:v>0} 2^(fma(q_i,k2_j,d_j)) - sum_{j:v<0} 2^(...)
//
// R16: pruning WITH broadcast preserved. R15 post-mortem: per-lane window
// starts made the hot-loop LDS address per-lane (32 addrs/wave) -> lost the
// wave-uniform ds_read_b128 broadcast; scattered reads ate the ~60% work
// cut. k4 additionally split each wave into two half-waves (jh=t>>5) paying
// for both halves' segments under exec-masking.
//  - k3: UNION window per 32-sorted-j group, from group-extreme k2 via
//    __shfl (all-pos -> suffix from smallest k2; all-neg -> prefix from
//    largest; mixed -> full). st/en block-uniform -> addresses depend only
//    on ih + loop idx -> 2 addrs/wave (free). Narrow-window lanes add
//    provably-negligible extra terms (more accurate, not less).
//  - k4: il=t&63, jh=t>>6 (wave-uniform segment set, 1 addr/wave) and
//    __all()-based wave-coherent segment skip (lanes = 64 consecutive
//    sorted q -> coherent ub).
// k0 (bucket sort), k1 (bf16 MFMA proj) unchanged.

#define D 2048
#define BATCH 32

// workspace float offsets
#define PART_STRIDE 196608   // one splitK part: 3*65536 (m*65536 + b*D + r)
#define BQV_OFF   786432     // bucketed q values [32][2048]
#define BQI_OFF   851968     // bucketed q orig index (int) [32][2048]
#define BK2_OFF   917504     // bucketed k2 values [32][2048]
#define BKI_OFF   983040     // bucketed k2 orig index (int) [32][2048]
#define META_OFF  1048576    // per b (stride 80): [0]qmx [1]qmn [2]scale, int off[65] at +8
#define PKD_OFF   1051136    // float2[32][64][32] two-ended segs (pos up, neg down)
#define NPT_OFF   1182208    // int[32][64] npos per seg
#define SMETA_OFF 1184256    // float4[32][64]: k2min,k2max,dmax per seg

#define L2E 1.4426950408889634f

typedef short s16x8 __attribute__((ext_vector_type(8)));
typedef float f32x4 __attribute__((ext_vector_type(4)));

union FragU { s16x8 v; unsigned u[4]; };

__device__ __forceinline__ float fast_exp2(float x) {
#if __has_builtin(__builtin_amdgcn_exp2f)
  return __builtin_amdgcn_exp2f(x);
#else
  return exp2f(x);
#endif
}
__device__ __forceinline__ int bits_below(unsigned long long m) {
  return __builtin_amdgcn_mbcnt_hi((unsigned)(m >> 32),
         __builtin_amdgcn_mbcnt_lo((unsigned)m, 0));
}
__device__ __forceinline__ unsigned pack_rne(float a, float b) {
  unsigned ua = __float_as_uint(a), ub = __float_as_uint(b);
  ua = ua + 0x7FFFu + ((ua >> 16) & 1u);
  ub = ub + 0x7FFFu + ((ub >> 16) & 1u);
  return (ua >> 16) | (ub & 0xFFFF0000u);
}
__device__ __forceinline__ void pack8(const float4& fa, const float4& fb,
                                      FragU& h) {
  h.u[0] = pack_rne(fa.x, fa.y);
  h.u[1] = pack_rne(fa.z, fa.w);
  h.u[2] = pack_rne(fb.x, fb.y);
  h.u[3] = pack_rne(fb.z, fb.w);
}
__device__ __forceinline__ float sum_parts(const float* __restrict__ ws,
                                           size_t o) {
  float s0 = ws[o] + ws[o + PART_STRIDE];
  float s1 = ws[o + 2 * PART_STRIDE] + ws[o + 3 * PART_STRIDE];
  return s0 + s1;
}

// ---------------- K1: projections via LDS-free bf16 MFMA -------------------
__global__ __launch_bounds__(256, 2) void k1_proj(
    const float* __restrict__ x, const float* __restrict__ Wq,
    const float* __restrict__ Wk, const float* __restrict__ Wv,
    float* __restrict__ ws) {
  __shared__ float red[4][512];
  const int tid = threadIdx.x;
  const int lane = tid & 63, wv = tid >> 6;
  const int tile = blockIdx.x >> 2, kq = blockIdx.x & 3;
  const int m = tile >> 7, lr = (tile & 127) * 16;
  const float* W = (m == 0) ? Wq : (m == 1) ? Wk : Wv;

  const int kbase = kq * 512 + wv * 128 + (lane >> 4) * 8;
  const float* ap = W + (size_t)(lr + (lane & 15)) * D + kbase;
  const float* xp0 = x + (size_t)(lane & 15) * D + kbase;
  const float* xp1 = xp0 + 16 * D;

  float4 fa[4], fb[4], x0a[4], x0b[4], x1a[4], x1b[4];
#pragma unroll
  for (int s = 0; s < 4; ++s) {
    const int off = s * 32;
    fa[s] = *(const float4*)(ap + off);
    fb[s] = *(const float4*)(ap + off + 4);
    x0a[s] = *(const float4*)(xp0 + off);
    x0b[s] = *(const float4*)(xp0 + off + 4);
    x1a[s] = *(const float4*)(xp1 + off);
    x1b[s] = *(const float4*)(xp1 + off + 4);
  }

  f32x4 acc0 = {0.f, 0.f, 0.f, 0.f}, acc1 = {0.f, 0.f, 0.f, 0.f};
#pragma unroll
  for (int s = 0; s < 4; ++s) {
    FragU Ah, Bh0, Bh1;
    pack8(fa[s], fb[s], Ah);
    pack8(x0a[s], x0b[s], Bh0);
    pack8(x1a[s], x1b[s], Bh1);
    acc0 = __builtin_amdgcn_mfma_f32_16x16x32_bf16(Ah.v, Bh0.v, acc0, 0, 0, 0);
    acc1 = __builtin_amdgcn_mfma_f32_16x16x32_bf16(Ah.v, Bh1.v, acc1, 0, 0, 0);
  }
  const int col = lane & 15, rq = (lane >> 4) * 4;
#pragma unroll
  for (int r = 0; r < 4; ++r) {
    red[wv][col * 16 + rq + r] = acc0[r];
    red[wv][(col + 16) * 16 + rq + r] = acc1[r];
  }
  __syncthreads();
  float* part = ws + (size_t)kq * PART_STRIDE + (size_t)m * 65536;
#pragma unroll
  for (int i = tid; i < 512; i += 256) {
    float s = (red[0][i] + red[1][i]) + (red[2][i] + red[3][i]);
    part[(size_t)(i >> 4) * D + lr + (i & 15)] = s;
  }
}

// ---------------- K0: bucketize q (pass 0) and k2 (pass 1) ----------------
// grid 64: b = bx&31, pass = bx>>5. 512 threads, 4 elements each. Value
// buckets (64, ascending), LDS-atomic counts, serial prefix, scatter with
// orig index. q pass also writes meta {qmx,qmn,scale,off[65]}.
__global__ __launch_bounds__(512) void k0_prep(float* __restrict__ ws,
                                               const float* __restrict__ bq,
                                               const float* __restrict__ bk) {
  __shared__ int cnt[64], off[65], cur[64];
  __shared__ float rmx[8], rmn[8];
  const int bx = blockIdx.x, t = threadIdx.x;
  const int b = bx & 31, pass = bx >> 5;
  const size_t qb = (size_t)b * D;
  float* meta = ws + META_OFF + b * 80;

  const size_t src = (pass ? 65536 : 0) + qb;
  float4 p0 = ((const float4*)(ws + src))[t];
  float4 p1 = ((const float4*)(ws + PART_STRIDE + src))[t];
  float4 p2 = ((const float4*)(ws + 2 * PART_STRIDE + src))[t];
  float4 p3 = ((const float4*)(ws + 3 * PART_STRIDE + src))[t];
  float4 bb = pass ? ((const float4*)bk)[t] : ((const float4*)bq)[t];
  float4 qv = {(p0.x + p1.x) + (p2.x + p3.x) + bb.x,
               (p0.y + p1.y) + (p2.y + p3.y) + bb.y,
               (p0.z + p1.z) + (p2.z + p3.z) + bb.z,
               (p0.w + p1.w) + (p2.w + p3.w) + bb.w};
  if (pass) {                       // k2 = (k + bk) * log2e
    qv.x *= L2E; qv.y *= L2E; qv.z *= L2E; qv.w *= L2E;
  }
  float mx = fmaxf(fmaxf(qv.x, qv.y), fmaxf(qv.z, qv.w));
  float mn = fminf(fminf(qv.x, qv.y), fminf(qv.z, qv.w));
#pragma unroll
  for (int o = 32; o; o >>= 1) {
    mx = fmaxf(mx, __shfl_down(mx, o));
    mn = fminf(mn, __shfl_down(mn, o));
  }
  if ((t & 63) == 0) { rmx[t >> 6] = mx; rmn[t >> 6] = mn; }
  if (t < 64) cnt[t] = 0;
  __syncthreads();
  mx = rmx[0]; mn = rmn[0];
#pragma unroll
  for (int w = 1; w < 8; ++w) {
    mx = fmaxf(mx, rmx[w]);
    mn = fminf(mn, rmn[w]);
  }
  const float scale = (mx > mn) ? 64.0f / (mx - mn) : 0.f;
  float vals[4] = {qv.x, qv.y, qv.z, qv.w};
  int bi[4];
#pragma unroll
  for (int e = 0; e < 4; ++e) {
    bi[e] = (int)fminf(63.f, fmaxf(0.f, (vals[e] - mn) * scale));
    atomicAdd(&cnt[bi[e]], 1);
  }
  __syncthreads();
  if (t == 0) {
    int a = 0;
#pragma unroll
    for (int i = 0; i < 64; ++i) { off[i] = a; cur[i] = a; a += cnt[i]; }
    off[64] = a;
  }
  __syncthreads();
  const size_t vdst = (pass ? BK2_OFF : BQV_OFF) + qb;
  const size_t idst = (pass ? BKI_OFF : BQI_OFF) + qb;
#pragma unroll
  for (int e = 0; e < 4; ++e) {
    const int pos = atomicAdd(&cur[bi[e]], 1);
    ws[vdst + pos] = vals[e];
    ((int*)ws)[idst + pos] = t * 4 + e;
  }
  if (pass == 0) {
    if (t == 0) { meta[0] = mx; meta[1] = mn; meta[2] = scale; }
    if (t < 65) ((int*)meta)[8 + t] = off[t];
  }
}

// ---------------- K3: union-window Z + finalize d + partition + seg meta ---
// grid 2048: b = bx&31, group g (32 sorted-k2 j) LPT-ordered (central
// full-window groups first). 512 thr = 32 j x 16 i-splits. Window = UNION
// over the group's 32 j (from group-extreme k2, block-uniform) -> hot-loop
// addresses depend only on ih + idx -> 2 addrs/wave broadcast. t<32
// finalizes, ballot-partitions the two-ended 32-seg, reduces seg meta.
__global__ __launch_bounds__(512, 8) void k3_z(float* __restrict__ ws,
                                               const float* __restrict__ bv) {
  __shared__ float qs[2048];
  __shared__ float zs[512];
  __shared__ int ob[65];
  const int bx = blockIdx.x, t = threadIdx.x;
  const int b = bx & 31, s = bx >> 5;
  const int g = (s & 1) ? 32 + (s >> 1) : 31 - (s >> 1);  // 31,32,30,33,...
  const size_t qb = (size_t)b * D;
  const float* meta = ws + META_OFF + b * 80;

  ((float4*)qs)[t] = ((const float4*)(ws + BQV_OFF + qb))[t];
  if (t < 65) ob[t] = ((const int*)meta)[8 + t];
  const float qmx = meta[0], qmn = meta[1], scale = meta[2];

  const int jl = t & 31, ih = t >> 5;
  const int p = g * 32 + jl;                 // bucketed (sorted) j position
  const float k2 = ws[BK2_OFF + qb + p];
  const int oj = ((const int*)ws)[BKI_OFF + qb + p];
  const float m2 = (k2 >= 0.f) ? k2 * qmx : k2 * qmn;
  const float nm2 = -m2;
  // group-extreme k2: lanes are 32 consecutive sorted k2 (repeated in the
  // upper half-wave), so lane 0 = smallest, lane 31 = largest.
  const float k2lo = __shfl(k2, 0);
  const float k2hi = __shfl(k2, 31);
  __syncthreads();

  int st, en;
  if (k2lo >= 0.f) {               // all-pos group: union = widest = k2lo
    const float c = qmx - 40.f / k2lo;       // k2lo==0 -> -inf -> full
    const int B = (int)fminf(63.f, fmaxf(0.f, (c - qmn) * scale));
    st = ob[B] & ~3; en = 2048;
  } else if (k2hi < 0.f) {         // all-neg group: union = widest = k2hi
    const float c = qmn + 40.f / (-k2hi);
    const int B = (int)fminf(63.f, fmaxf(0.f, (c - qmn) * scale));
    st = 0; en = (ob[B + 1] + 3) & ~3;
  } else {                         // mixed-sign: full window
    st = 0; en = 2048;
  }
  const int nq = (en - st) >> 2;
  const int i0 = st + (((nq * ih) >> 4) << 2);
  const int i1 = st + (((nq * (ih + 1)) >> 4) << 2);
  float z0 = 0.f, z1 = 0.f, z2 = 0.f, z3 = 0.f;
  for (int idx = i0; idx < i1; idx += 4) {
    float4 q4 = *(const float4*)&qs[idx];    // 2 addrs/wave -> broadcast
    z0 += fast_exp2(fmaf(q4.x, k2, nm2));
    z1 += fast_exp2(fmaf(q4.y, k2, nm2));
    z2 += fast_exp2(fmaf(q4.z, k2, nm2));
    z3 += fast_exp2(fmaf(q4.w, k2, nm2));
  }
  zs[ih * 32 + jl] = (z0 + z1) + (z2 + z3);
  __syncthreads();

  if (t < 32) {                              // wave 0, lanes 0-31
    float Z = 0.f;
#pragma unroll
    for (int h = 0; h < 16; ++h) Z += zs[h * 32 + t];
    const float v = sum_parts(ws, 131072 + qb + oj) + bv[oj];
    const float d = __log2f(fabsf(v) / Z) - m2;  // v==0 -> -inf -> 2^ -> 0
    const unsigned long long msk = __ballot(v >= 0.f);
    const int npos = __popcll(msk);
    const int slot = (v >= 0.f) ? bits_below(msk)
                                : 31 - bits_below(~msk & 0xFFFFFFFFull);
    float2* dst = (float2*)(ws + PKD_OFF) + ((size_t)b * 64 + g) * 32;
    dst[slot] = make_float2(k2, d);
    if (t == 0) ((int*)(ws + NPT_OFF))[b * 64 + g] = npos;
    float kmn = k2, kmx = k2, dmx = d;       // seg meta over 32 lanes
#pragma unroll
    for (int o = 16; o; o >>= 1) {
      kmn = fminf(kmn, __shfl_down(kmn, o, 32));
      kmx = fmaxf(kmx, __shfl_down(kmx, o, 32));
      dmx = fmaxf(dmx, __shfl_down(dmx, o, 32));
    }
    if (t == 0)
      ((float4*)(ws + SMETA_OFF))[b * 64 + g] =
          make_float4(kmn, kmx, dmx, 0.f);
  }
}

// ---------------- K4: out over segs, wave-coherent skip --------------------
// grid 1024: b = bx&31, ic LPT-ordered (extreme-q blocks first; 64 i each).
// Thread t: i = ic*64 + (t&63) (64 consecutive sorted q per wave), seg-
// eighth jh = t>>6 (wave-uniform; 8 segs of 32 per wave -> 1 addr/wave
// broadcast). Per-seg skip via __all(ub < -28): coherent since lanes hold
// similar q; non-skipping lanes add negligible extras. Scatter to orig i.
__global__ __launch_bounds__(512, 8) void k4_out(const float* __restrict__ ws,
                                                 float* __restrict__ out) {
  __shared__ float2 kd[2048];
  __shared__ float4 sm[64];
  __shared__ int np[64];
  __shared__ float rs[64 * 9];
  const int bx = blockIdx.x, t = threadIdx.x;
  const int b = bx & 31, s = bx >> 5;
  const int ic = (s & 1) ? 31 - (s >> 1) : (s >> 1);   // 0,31,1,30,...
  const size_t qb = (size_t)b * D;

  const float4* src = (const float4*)((const float2*)(ws + PKD_OFF) +
                                      (size_t)b * 2048);
  ((float4*)kd)[t] = src[t];
  ((float4*)kd)[t + 512] = src[t + 512];
  if (t < 64) {
    np[t] = ((const int*)(ws + NPT_OFF))[b * 64 + t];
    sm[t] = ((const float4*)(ws + SMETA_OFF))[b * 64 + t];
  }
  const int il = t & 63, jh = t >> 6;
  const int pos = ic * 64 + il;              // bucketed (sorted) q position
  const float qi = ws[BQV_OFF + qb + pos];
  const int oi = ((const int*)ws)[BQI_OFF + qb + pos];
  __syncthreads();

  float p0 = 0.f, p1 = 0.f, p2 = 0.f, p3 = 0.f;
  float n0 = 0.f, n1 = 0.f, n2 = 0.f, n3 = 0.f;
#pragma unroll
  for (int s8 = 0; s8 < 8; ++s8) {
    const int sg = jh * 8 + s8;
    const float4 m = sm[sg];
    const float ub = fmaxf(m.x * qi, m.y * qi) + m.z;
    if (__all(ub < -28.f)) continue;         // whole wave skips the seg
    const float4* seg = (const float4*)(kd + sg * 32);
    const int npos = np[sg], gb = npos >> 2;
    for (int gq = 0; gq < gb; ++gq) {        // all-pos quads
      float4 a = seg[gq * 2], c = seg[gq * 2 + 1];
      p0 += fast_exp2(fmaf(qi, a.x, a.y));
      p1 += fast_exp2(fmaf(qi, a.z, a.w));
      p2 += fast_exp2(fmaf(qi, c.x, c.y));
      p3 += fast_exp2(fmaf(qi, c.z, c.w));
    }
    if (gb < 8) {
      {                                      // boundary quad: selects
        float4 a = seg[gb * 2], c = seg[gb * 2 + 1];
        const int base = gb * 4;
        float e0 = fast_exp2(fmaf(qi, a.x, a.y));
        float e1 = fast_exp2(fmaf(qi, a.z, a.w));
        float e2 = fast_exp2(fmaf(qi, c.x, c.y));
        float e3 = fast_exp2(fmaf(qi, c.z, c.w));
        if (base + 0 < npos) p0 += e0; else n0 += e0;
        if (base + 1 < npos) p1 += e1; else n1 += e1;
        if (base + 2 < npos) p2 += e2; else n2 += e2;
        if (base + 3 < npos) p3 += e3; else n3 += e3;
      }
      for (int gq = gb + 1; gq < 8; ++gq) {  // all-neg quads
        float4 a = seg[gq * 2], c = seg[gq * 2 + 1];
        n0 += fast_exp2(fmaf(qi, a.x, a.y));
        n1 += fast_exp2(fmaf(qi, a.z, a.w));
        n2 += fast_exp2(fmaf(qi, c.x, c.y));
        n3 += fast_exp2(fmaf(qi, c.z, c.w));
      }
    }
  }
  rs[il * 9 + jh] = ((p0 + p1) + (p2 + p3)) - ((n0 + n1) + (n2 + n3));
  __syncthreads();
  if (t < 64) {
    float sum = 0.f;
#pragma unroll
    for (int h = 0; h < 8; ++h) sum += rs[t * 9 + h];
    out[qb + oi] = sum;                      // scatter to orig i
  }
}

extern "C" void kernel_launch(void* const* d_in, const int* in_sizes, int n_in,
                              void* d_out, int out_size, void* d_ws, size_t ws_size,
                              hipStream_t stream) {
  (void)in_sizes; (void)n_in; (void)out_size; (void)ws_size;
  const float* x  = (const float*)d_in[0];
  const float* Wq = (const float*)d_in[1];
  const float* bq = (const float*)d_in[2];
  const float* bk = (const float*)d_in[4];
  const float* Wk = (const float*)d_in[3];
  const float* Wv = (const float*)d_in[5];
  const float* bv = (const float*)d_in[6];
  float* ws  = (float*)d_ws;
  float* out = (float*)d_out;

  k1_proj<<<1536, 256, 0, stream>>>(x, Wq, Wk, Wv, ws);
  k0_prep<<<64, 512, 0, stream>>>(ws, bq, bk);
  k3_z<<<2048, 512, 0, stream>>>(ws, bv);
  k4_out<<<1024, 512, 0, stream>>>(ws, out);
}